// Round 9
// baseline (223.997 us; speedup 1.0000x reference)
//
#include <hip/hip_runtime.h>
#include <stdint.h>

#define N_IMG 256
#define HW 196
#define CDIM 512
#define NPT 7                        // 7 p-tiles of 32 rows (last: 4 valid)

#define F_EPS_POS 0.65f
#define F_EPS_NEG 0.40f
#define F_INV_TAU (1.0f/0.03f)
#define F_TEMP 0.07f

typedef __attribute__((ext_vector_type(8))) short bf16x8;
typedef __attribute__((ext_vector_type(4))) unsigned short u16x4;
typedef __attribute__((ext_vector_type(4))) float f32x4;

__device__ __forceinline__ unsigned short f2bf(float x){
    unsigned int u = __float_as_uint(x);
    u = (u + 0x7FFFu + ((u >> 16) & 1u)) >> 16;
    return (unsigned short)u;
}
__device__ __forceinline__ float sigm(float x){ return 1.0f/(1.0f + __expf(-x)); }

// ---------------- kernel 1: audio L2-normalize -> bf16 ----------------
__global__ void audio_norm_k(const float* __restrict__ audio,
                             unsigned short* __restrict__ abf){
    int k = blockIdx.x, t = threadIdx.x;
    __shared__ float red[256];
    float v0 = audio[k*CDIM + t];
    float v1 = audio[k*CDIM + t + 256];
    red[t] = v0*v0 + v1*v1;
    __syncthreads();
    for (int s = 128; s > 0; s >>= 1){
        if (t < s) red[t] += red[t+s];
        __syncthreads();
    }
    float rrt = 1.0f / sqrtf(red[0]);
    abf[k*CDIM + t]       = f2bf(v0*rrt);
    abf[k*CDIM + t + 256] = f2bf(v1*rrt);
}

// ---------------- kernel 2: FLATTENED main GEMM ----------------
// ROUND-9: rounds 0-8 all ran ONE long-lived block per CU serializing 8-13
// stage->barrier->compute phases; no other block could overlap the stalls,
// and main_k was invariant at ~58-76us with no pipe >30%. This version
// flattens the loop into the grid: one block = one (n, 32-row p-tile).
// grid = 7*256 = 1792 blocks, 512 thr (8 waves, 32 k-cols/wave -> all 256 k).
// Block life: ONE coalesced staging burst (32x512 fp32, 128B/thread) with
// r2's exact convert/ss/butterfly, ONE barrier, 32 ds_read + 64 MFMA per
// wave, epilogue, exit. No K-loop, no double-buffer: inter-block TLP (7
// blocks/CU queued) replaces all hand-rolled pipelining. B (audio) frags
// are block-invariant (depend only on k) -> L2-hot reload each block.
// Partial sums per p-tile go to disjoint arrays (deterministic); pd_k sums.
__global__ __launch_bounds__(512) __attribute__((amdgpu_waves_per_eu(2)))
void main_k(const float* __restrict__ frame,
            const unsigned short* __restrict__ abf,
            float* __restrict__ np, float* __restrict__ dp,
            float* __restrict__ hnp, float* __restrict__ hdp){
    __shared__ unsigned short A[32*520];     // 520 stride: conflict-free b128
    __shared__ float rnS[32];

    const int t    = threadIdx.x;
    const int n    = blockIdx.x & 255;
    const int pt   = blockIdx.x >> 8;        // 0..6
    const int lane = t & 63, wid = t >> 6;   // wid 0..7
    const int col  = lane & 15, quad = lane >> 4;
    const int kg0  = wid*32 + col;           // this wave's two k columns
    const int kg1  = kg0 + 16;

    // ---- B fragments in registers (2 x 16 x bf16x8 = 128 VGPRs) ----
    bf16x8 B0[16], B1[16];
    {
        const unsigned short* b0p = abf + (size_t)kg0*CDIM + quad*8;
        const unsigned short* b1p = abf + (size_t)kg1*CDIM + quad*8;
        #pragma unroll
        for (int j = 0; j < 16; ++j){
            B0[j] = *(const bf16x8*)(b0p + j*32);
            B1[j] = *(const bf16x8*)(b1p + j*32);
        }
    }
#define ANCH8(a,b,c,d,e,f,g,h) \
    asm volatile("" : "+v"(a),"+v"(b),"+v"(c),"+v"(d),"+v"(e),"+v"(f),"+v"(g),"+v"(h))
    ANCH8(B0[0],B0[1],B0[2],B0[3],B0[4],B0[5],B0[6],B0[7]);
    ANCH8(B0[8],B0[9],B0[10],B0[11],B0[12],B0[13],B0[14],B0[15]);
    ANCH8(B1[0],B1[1],B1[2],B1[3],B1[4],B1[5],B1[6],B1[7]);
    ANCH8(B1[8],B1[9],B1[10],B1[11],B1[12],B1[13],B1[14],B1[15]);
#undef ANCH8

    // ---- single staging burst: wave w owns rows w*4..w*4+3 ----
    {
        const float4* fbase_g = (const float4*)(frame + (size_t)n*HW*CDIM);
        float4 v[8];
        int rr0 = wid*4;
        #pragma unroll
        for (int i = 0; i < 4; ++i){
            int prow = pt*32 + rr0 + i; if (prow > HW-1) prow = HW-1;  // clamp
            const float4* s = fbase_g + (size_t)prow*(CDIM/4);
            v[2*i]   = s[lane];
            v[2*i+1] = s[lane + 64];
        }
        #pragma unroll
        for (int i = 0; i < 4; ++i){
            float ss = v[2*i].x*v[2*i].x + v[2*i].y*v[2*i].y
                     + v[2*i].z*v[2*i].z + v[2*i].w*v[2*i].w
                     + v[2*i+1].x*v[2*i+1].x + v[2*i+1].y*v[2*i+1].y
                     + v[2*i+1].z*v[2*i+1].z + v[2*i+1].w*v[2*i+1].w;
            unsigned short* d = A + (rr0 + i)*520;
            u16x4 u0 = { f2bf(v[2*i].x),   f2bf(v[2*i].y),
                         f2bf(v[2*i].z),   f2bf(v[2*i].w) };
            u16x4 u1 = { f2bf(v[2*i+1].x), f2bf(v[2*i+1].y),
                         f2bf(v[2*i+1].z), f2bf(v[2*i+1].w) };
            *(u16x4*)(d + lane*4)       = u0;
            *(u16x4*)(d + 256 + lane*4) = u1;
            #pragma unroll
            for (int dd = 1; dd < 64; dd <<= 1) ss += __shfl_xor(ss, dd, 64);
            if (lane == 0)
                rnS[rr0 + i] = (ss > 0.f) ? (1.0f/sqrtf(ss)) : 0.f;
        }
    }
    __syncthreads();

    // ---- MFMA burst: 2 row-frags x 2 k-chains x 16 j = 64 MFMAs ----
    f32x4 a00 = {0.f,0.f,0.f,0.f}, a01 = {0.f,0.f,0.f,0.f};
    f32x4 a10 = {0.f,0.f,0.f,0.f}, a11 = {0.f,0.f,0.f,0.f};
    {
        const unsigned short* fb0 = A + col*520 + quad*8;          // rows 0..15
        const unsigned short* fb1 = A + (16 + col)*520 + quad*8;   // rows 16..31
        #pragma unroll
        for (int j = 0; j < 16; ++j){
            bf16x8 x0 = *(const bf16x8*)(fb0 + j*32);
            bf16x8 x1 = *(const bf16x8*)(fb1 + j*32);
            a00 = __builtin_amdgcn_mfma_f32_16x16x32_bf16(x0, B0[j], a00, 0, 0, 0);
            a01 = __builtin_amdgcn_mfma_f32_16x16x32_bf16(x0, B1[j], a01, 0, 0, 0);
            a10 = __builtin_amdgcn_mfma_f32_16x16x32_bf16(x1, B0[j], a10, 0, 0, 0);
            a11 = __builtin_amdgcn_mfma_f32_16x16x32_bf16(x1, B1[j], a11, 0, 0, 0);
        }
    }

    // ---- epilogue: weighted reductions over this tile's valid rows ----
    float en0=0.f, en1=0.f, ed0=0.f, ed1=0.f;
    float hn0=0.f, hn1=0.f, hd0=0.f, hd1=0.f;
    #pragma unroll
    for (int m = 0; m < 2; ++m){
        const f32x4& c0 = m ? a10 : a00;
        const f32x4& c1 = m ? a11 : a01;
        #pragma unroll
        for (int rr = 0; rr < 4; ++rr){
            int row  = m*16 + quad*4 + rr;     // 0..31
            int prow = pt*32 + row;
            if (prow < HW){
                float rn = rnS[row];
                float s0 = c0[rr] * rn;
                float s1 = c1[rr] * rn;
                float w0 = sigm((s0 - F_EPS_POS) * F_INV_TAU);
                float w1 = sigm((s1 - F_EPS_POS) * F_INV_TAU);
                en0 += w0*s0; ed0 += w0;
                en1 += w1*s1; ed1 += w1;
                if (kg0 == n){ float wn = 1.f - sigm((s0 - F_EPS_NEG) * F_INV_TAU); hn0 += wn*s0; hd0 += wn; }
                if (kg1 == n){ float wn = 1.f - sigm((s1 - F_EPS_NEG) * F_INV_TAU); hn1 += wn*s1; hd1 += wn; }
            }
        }
    }

    en0 += __shfl_xor(en0, 16, 64); en0 += __shfl_xor(en0, 32, 64);
    ed0 += __shfl_xor(ed0, 16, 64); ed0 += __shfl_xor(ed0, 32, 64);
    en1 += __shfl_xor(en1, 16, 64); en1 += __shfl_xor(en1, 32, 64);
    ed1 += __shfl_xor(ed1, 16, 64); ed1 += __shfl_xor(ed1, 32, 64);
    hn0 += __shfl_xor(hn0, 16, 64); hn0 += __shfl_xor(hn0, 32, 64);
    hd0 += __shfl_xor(hd0, 16, 64); hd0 += __shfl_xor(hd0, 32, 64);
    hn1 += __shfl_xor(hn1, 16, 64); hn1 += __shfl_xor(hn1, 32, 64);
    hd1 += __shfl_xor(hd1, 16, 64); hd1 += __shfl_xor(hd1, 32, 64);

    if (quad == 0){
        float* npp = np + (size_t)pt*N_IMG*N_IMG + n*N_IMG;
        float* dpp = dp + (size_t)pt*N_IMG*N_IMG + n*N_IMG;
        npp[kg0] = en0;  dpp[kg0] = ed0;
        npp[kg1] = en1;  dpp[kg1] = ed1;
        if (kg0 == n){ hnp[pt*N_IMG + n] = hn0; hdp[pt*N_IMG + n] = hd0; }
        if (kg1 == n){ hnp[pt*N_IMG + n] = hn1; hdp[pt*N_IMG + n] = hd1; }
    }
}

// ---------------- kernel 3: per-n Pi_d / Ni_d (sums the 7 p-tile partials) ----------------
__global__ void pd_k(const float* __restrict__ np, const float* __restrict__ dp,
                     const float* __restrict__ hnp, const float* __restrict__ hdp,
                     float* __restrict__ Pi_d, float* __restrict__ Ni_d){
    int nn = blockIdx.x, t = threadIdx.x;
    __shared__ float red[256];
    __shared__ float diagv;
    float nsum = 0.f, dsum = 0.f;
    #pragma unroll
    for (int ptile = 0; ptile < NPT; ++ptile){
        nsum += np[(size_t)ptile*N_IMG*N_IMG + nn*N_IMG + t];
        dsum += dp[(size_t)ptile*N_IMG*N_IMG + nn*N_IMG + t];
    }
    float ratio = nsum / dsum;
    if (t == nn) diagv = ratio;
    red[t] = ratio * (t == nn ? -99.f : 1.f);
    __syncthreads();
    for (int s = 128; s > 0; s >>= 1){
        if (t < s) red[t] += red[t+s];
        __syncthreads();
    }
    if (t == 0){
        float hn = 0.f, hd = 0.f;
        #pragma unroll
        for (int ptile = 0; ptile < NPT; ++ptile){
            hn += hnp[ptile*N_IMG + nn];
            hd += hdp[ptile*N_IMG + nn];
        }
        Pi_d[nn] = F_TEMP * diagv;
        Ni_d[nn] = F_TEMP * (hn/hd + red[0]);
    }
}

// ---------------- kernel 4: broadcast (N,N) log-sum + atomic total ----------------
__global__ void loss_k(const float* __restrict__ Pi_d, const float* __restrict__ Ni_d,
                       float* __restrict__ out){
    int i = blockIdx.x, j = threadIdx.x;
    __shared__ float red[256];
    float x = Ni_d[j] - Pi_d[i];
    red[j] = (x > 20.f) ? x : log1pf(__expf(x));
    __syncthreads();
    for (int s = 128; s > 0; s >>= 1){
        if (j < s) red[j] += red[j+s];
        __syncthreads();
    }
    if (j == 0) atomicAdd(out, red[0] * (1.0f/(float)N_IMG));
}

extern "C" void kernel_launch(void* const* d_in, const int* in_sizes, int n_in,
                              void* d_out, int out_size, void* d_ws, size_t ws_size,
                              hipStream_t stream) {
    const float* frame = (const float*)d_in[0];
    const float* audio = (const float*)d_in[1];
    float* out = (float*)d_out;
    char* ws = (char*)d_ws;

    unsigned short* abf = (unsigned short*)(ws);            // 262144 B
    float* np   = (float*)(ws + 262144);                    // 1835008 B
    float* dp   = (float*)(ws + 2097152);                   // 1835008 B
    float* hnp  = (float*)(ws + 3932160);                   // 7168 B
    float* hdp  = (float*)(ws + 3940352);                   // 7168 B
    float* Pi_d = (float*)(ws + 3948544);                   // 1024 B
    float* Ni_d = (float*)(ws + 3949568);                   // 1024 B

    hipMemsetAsync(out, 0, sizeof(float), stream);          // capture-legal

    audio_norm_k<<<N_IMG, 256, 0, stream>>>(audio, abf);
    main_k<<<NPT*N_IMG, 512, 0, stream>>>(frame, abf, np, dp, hnp, hdp);
    pd_k<<<N_IMG, 256, 0, stream>>>(np, dp, hnp, hdp, Pi_d, Ni_d);
    loss_k<<<N_IMG, 256, 0, stream>>>(Pi_d, Ni_d, out);
}